// Round 1
// baseline (175.241 us; speedup 1.0000x reference)
//
#include <hip/hip_runtime.h>

#define BATCH_N   16384
#define NFIELDS   20
#define FIELD_DIM 50000
#define ROW_W     32   // emb row width in floats
#define FPG       5    // fields per quarter-group

typedef float f32x4 __attribute__((ext_vector_type(4)));

// 32 threads per batch row:
//   d = t & 7  : dim group, owns dims [4d, 4d+4) of the 32-float emb row
//   q = t >> 3 : field quarter, owns fields [5q, 5q+5)
// Per-thread e1/e2/e3 DP over 5 fields, then 2-level shfl_xor combine across
// field quarters (ESP merge rule), then 8-lane dim reduction.
// Entire problem (524288 threads) is co-resident: one full-occupancy pass.
//
// Loads are CACHED (not nontemporal) this round:
//  - lin: 4 MB table, ~5.2 accesses per 64B line -> L2/L3 resident. NT was
//    paying a full DRAM burst per 4B gather (~21 MB fetch for 4 MB of data).
//  - emb: 327,680 gathers over ~278K distinct rows; the 128 MB table fits in
//    the 256 MB L3, so the ~18% duplicate rows become L3 hits instead of
//    repeat HBM fetches.
__global__ __launch_bounds__(256) void hofm_kernel(
    const int*   __restrict__ x,
    const float* __restrict__ emb,
    const float* __restrict__ lin,
    const float* __restrict__ bias,
    float*       __restrict__ out)
{
    const int tid = blockIdx.x * blockDim.x + threadIdx.x;
    const int row = tid >> 5;
    const int t   = tid & 31;
    const int d   = t & 7;
    const int q   = t >> 3;
    if (row >= BATCH_N) return;

    const int* xr = x + row * NFIELDS + q * FPG;

    // lin gather issued first; index recomputed from xr[d] (L1-hit broadcast
    // line) to avoid runtime-indexing the idx[] register array (scratch risk).
    float linsum = 0.f;
    if (d < FPG)
        linsum = lin[xr[d] + (q * FPG + d) * FIELD_DIM];

    // load all 5 indices (broadcast across the 8 d-lanes of a quarter)
    int idx[FPG];
    #pragma unroll
    for (int j = 0; j < FPG; ++j)
        idx[j] = xr[j] + (q * FPG + j) * FIELD_DIM;

    // issue all emb gathers (cached), then do the DP math
    f32x4 v[FPG];
    #pragma unroll
    for (int j = 0; j < FPG; ++j)
        v[j] = *(const f32x4*)(emb + (size_t)idx[j] * ROW_W + d * 4);

    float a1[4] = {0.f, 0.f, 0.f, 0.f};
    float a2[4] = {0.f, 0.f, 0.f, 0.f};
    float a3[4] = {0.f, 0.f, 0.f, 0.f};

    #pragma unroll
    for (int j = 0; j < FPG; ++j) {
        #pragma unroll
        for (int k = 0; k < 4; ++k) {
            const float vv = v[j][k];
            a3[k] += vv * a2[k];
            a2[k] += vv * a1[k];
            a1[k] += vv;
        }
    }

    // combine field quarters: lane xor 8, then xor 16
    #pragma unroll
    for (int lvl = 0; lvl < 2; ++lvl) {
        const int mask = 8 << lvl;
        #pragma unroll
        for (int k = 0; k < 4; ++k) {
            const float p1 = __shfl_xor(a1[k], mask, 32);
            const float p2 = __shfl_xor(a2[k], mask, 32);
            const float p3 = __shfl_xor(a3[k], mask, 32);
            a3[k] = a3[k] + p3 + a2[k] * p1 + a1[k] * p2;
            a2[k] = a2[k] + p2 + a1[k] * p1;
            a1[k] = a1[k] + p1;
        }
    }

    const float espsum = (d < 4) ? (a2[0] + a2[1] + a2[2] + a2[3])
                                 : (a3[0] + a3[1] + a3[2] + a3[3]);
    // esp values are replicated across quarters post-combine; count once
    float partial = ((q == 0) ? espsum : 0.f) + linsum;

    // reduce across the 32 lanes of this row
    partial += __shfl_down(partial, 16, 32);
    partial += __shfl_down(partial,  8, 32);
    partial += __shfl_down(partial,  4, 32);
    partial += __shfl_down(partial,  2, 32);
    partial += __shfl_down(partial,  1, 32);

    if (t == 0) out[row] = partial + bias[0];
}

extern "C" void kernel_launch(void* const* d_in, const int* in_sizes, int n_in,
                              void* d_out, int out_size, void* d_ws, size_t ws_size,
                              hipStream_t stream) {
    const int*   x    = (const int*)  d_in[0];
    const float* emb  = (const float*)d_in[1];
    const float* lin  = (const float*)d_in[2];
    const float* bias = (const float*)d_in[3];
    float*       out  = (float*)d_out;

    const int total_threads = BATCH_N * 32;
    const int block = 256;
    const int grid  = (total_threads + block - 1) / block;
    hofm_kernel<<<grid, block, 0, stream>>>(x, emb, lin, bias, out);
}